// Round 10
// baseline (65.967 us; speedup 1.0000x reference)
//
#include <hip/hip_runtime.h>

namespace {

constexpr int kC = 32;
constexpr int kD = 512;
constexpr int kB = 512;
constexpr int kN = 1024;               // 2B rows (source ++ target)
constexpr int kCD = kC * kD;           // floats per batch index i
constexpr int BM = 256;                // block tile (256x256)
constexpr int BKt = 32;                // K chunk (bf16 elements)
constexpr int KT = kD / BKt;           // 16
constexpr int T2 = kN / BM;            // 4 panels per side
constexpr int NP = T2 * (T2 + 1) / 2;  // 10 triangular pairs

typedef float f32x4 __attribute__((ext_vector_type(4)));
typedef short s16x8 __attribute__((ext_vector_type(8)));

// pack two f32 to bf16 (RNE) into one u32: a -> low half, b -> high half
__device__ inline unsigned int pack_bf16(float a, float b) {
  unsigned int ua = __float_as_uint(a);
  unsigned int ub = __float_as_uint(b);
  ua += 0x7fffu + ((ua >> 16) & 1u);   // round-to-nearest-even
  ub += 0x7fffu + ((ub >> 16) & 1u);
  return (ua >> 16) | (ub & 0xffff0000u);
}

// Pass 1: tot[c][i][d] = bf16(total[i,c,d]); sq[c*kN+i] = sum_d total^2 (f32).
// One wave per (i,c) row of 512 floats. Also zeroes d_out (replaces memset).
__global__ void prep_kernel(const float* __restrict__ src,
                            const float* __restrict__ tgt,
                            float* __restrict__ sq,
                            unsigned int* __restrict__ tot,
                            float* __restrict__ out) {
  if (blockIdx.x == 0 && threadIdx.x == 0) *out = 0.f;
  int gw = (blockIdx.x * blockDim.x + threadIdx.x) >> 6;
  int lane = threadIdx.x & 63;
  int i = gw >> 5;
  int c = gw & 31;
  const float* p = (i < kB ? src + (size_t)i * kCD
                           : tgt + (size_t)(i - kB) * kCD) + c * kD;
  f32x4 v0 = *(const f32x4*)(p + lane * 8);
  f32x4 v1 = *(const f32x4*)(p + lane * 8 + 4);

  uint4 w = make_uint4(pack_bf16(v0.x, v0.y), pack_bf16(v0.z, v0.w),
                       pack_bf16(v1.x, v1.y), pack_bf16(v1.z, v1.w));
  *(uint4*)(tot + (size_t)(c * kN + i) * (kD / 2) + lane * 4) = w;

  float s = v0.x * v0.x + v0.y * v0.y + v0.z * v0.z + v0.w * v0.w
          + v1.x * v1.x + v1.y * v1.y + v1.z * v1.z + v1.w * v1.w;
#pragma unroll
  for (int o = 32; o > 0; o >>= 1) s += __shfl_down(s, o);
  if (lane == 0) sq[c * kN + i] = s;
}

// Pass 2: 256x256 tile per block (10 triangular pairs x 32 ch = 320 blocks),
// 8 waves of 128x64 each (wr=wid>>2 row-half, wc=wid&3 col-quarter).
// 2-deep LDS (64 KB -> 2 blocks/CU), one vmcnt(0)+barrier per K-step (the
// vmcnt waits loads issued a full step earlier => cheap), stage-next issued
// immediately after the barrier, setprio around the MFMA cluster.
// LDS layout per 16KB panel buffer: row r (0..255, 64B), 16B chunk q at byte
// S(r,q) = (r>>1)*128 + (r&1)*64 + (q ^ ((r>>1)&3))*16   [R4..R9-verified].
__launch_bounds__(512, 2)
__global__ void mmd_kernel(const unsigned short* __restrict__ tot,
                           const float* __restrict__ sq,
                           float* __restrict__ out) {
  const int b = blockIdx.x;
  const int c = b & 31;          // b = p*32 + c -> b%8 == c%8 (XCD pin)
  int p = b >> 5;                // 0..9
  int ti = 0;
  while (p >= T2 - ti) { p -= T2 - ti; ++ti; }
  const int tj = ti + p;

  __shared__ __align__(16) unsigned short lA[2][BM * BKt];  // 2 x 16KB
  __shared__ __align__(16) unsigned short lB[2][BM * BKt];
  __shared__ float wsum[8];

  const int t = threadIdx.x;
  const int lane = t & 63;
  const int wid = t >> 6;        // 0..7
  const int wr = wid >> 2;       // row-half: rows wr*128 .. +127
  const int wc = wid & 3;        // col-quarter: cols wc*64 .. +63

  const unsigned short* gA = tot + (size_t)(c * kN + ti * BM) * kD;
  const unsigned short* gB = tot + (size_t)(c * kN + tj * BM) * kD;

  // staging: segment s (1KB) covers rows 16s..16s+15; wave w owns segments
  // {2w, 2w+1} of A and of B (4 global_load_lds per wave per step).
  // lane l's 16B at linear s*1024+l*16 holds row 16s+srow, chunk scch:
  const int srow = ((lane >> 3) << 1) + ((lane >> 2) & 1);
  const int scch = (lane & 3) ^ ((lane >> 3) & 3);

  auto STAGE = [&](int buf, int ks) {
#pragma unroll
    for (int q = 0; q < 2; ++q) {
      int seg = wid * 2 + q;
      int r = 16 * seg + srow;
      size_t off = (size_t)r * kD + ks * BKt + scch * 8;
      __builtin_amdgcn_global_load_lds(
          (const __attribute__((address_space(1))) unsigned int*)(gA + off),
          (__attribute__((address_space(3))) unsigned int*)&lA[buf][seg * 512],
          16, 0, 0);
      __builtin_amdgcn_global_load_lds(
          (const __attribute__((address_space(1))) unsigned int*)(gB + off),
          (__attribute__((address_space(3))) unsigned int*)&lB[buf][seg * 512],
          16, 0, 0);
    }
  };

  // fragment-read lane offset (bytes): row 16m + (lane&15), k-chunk lane>>4;
  // swizzle term lane-only -> m/n offsets are compile-time immediates.
  const int l15 = lane & 15;
  const int s4 = lane >> 4;
  const int laneoff = ((l15 >> 1) << 7) + ((l15 & 1) << 6) +
                      ((s4 ^ ((l15 >> 1) & 3)) << 4);

  f32x4 acc[8][4] = {};

  STAGE(0, 0);

#pragma unroll
  for (int ks = 0; ks < KT; ++ks) {
    // my stage loads for this step were issued a full step ago -> cheap wait;
    // barrier then publishes ALL waves' completed stages.
    asm volatile("s_waitcnt vmcnt(0)" ::: "memory");
    __builtin_amdgcn_sched_barrier(0);
    __builtin_amdgcn_s_barrier();

    const int buf = ks & 1;
    if (ks + 1 < KT) STAGE(buf ^ 1, ks + 1);

    const char* Abase = (const char*)lA[buf] + wr * 8192 + laneoff;
    const char* Bbase = (const char*)lB[buf] + wc * 4096 + laneoff;
    s16x8 aF[8], bF[4];
#pragma unroll
    for (int m = 0; m < 8; ++m) aF[m] = *(const s16x8*)(Abase + m * 1024);
#pragma unroll
    for (int n = 0; n < 4; ++n) bF[n] = *(const s16x8*)(Bbase + n * 1024);

    __builtin_amdgcn_s_setprio(1);
#pragma unroll
    for (int m = 0; m < 8; ++m)
#pragma unroll
      for (int n = 0; n < 4; ++n)
        acc[m][n] = __builtin_amdgcn_mfma_f32_16x16x32_bf16(
            aF[m], bF[n], acc[m][n], 0, 0, 0);
    __builtin_amdgcn_s_setprio(0);
  }

  // epilogue: L2 = sq_i + sq_j - 2*cross; 5-sigma kernel via repeated
  // squaring. acc[m][n] reg rI -> row ti*256+wr*128+m*16+s4*4+rI,
  // col tj*256+wc*64+n*16+l15.
  const float sgn = ((ti < 2) == (tj < 2)) ? 1.f : -1.f;
  const float scale = sgn / 262144.f;       // / B^2
  const bool diag = (ti == tj);             // block-uniform
  const float* sqA = sq + c * kN + ti * BM + wr * 128;
  const float* sqB = sq + c * kN + tj * BM + wc * 64;

  float local = 0.f;
#pragma unroll
  for (int m = 0; m < 8; ++m) {
    float sqa_r[4];
#pragma unroll
    for (int rI = 0; rI < 4; ++rI)
      sqa_r[rI] = sqA[m * 16 + s4 * 4 + rI];
#pragma unroll
    for (int n = 0; n < 4; ++n) {
      float sqb_ = sqB[n * 16 + l15];
#pragma unroll
      for (int rI = 0; rI < 4; ++rI) {
        float L2 = sqa_r[rI] + sqb_ - 2.f * acc[m][n][rI];
        float tt = __expf(L2 * -0.0625f);  // exp(-L2/16)
        float t2 = tt * tt, t4 = t2 * t2, t8 = t4 * t4;
        float sumt = tt + t2 + t4 + t8 + t8 * t8;
        if (diag) {
          int gr = wr * 128 + m * 16 + s4 * 4 + rI;
          int gc = wc * 64 + n * 16 + l15;
          float w = gr < gc ? 2.f : (gr == gc ? 1.f : 0.f);
          local += w * sumt;
        } else {
          local += 2.f * sumt;
        }
      }
    }
  }
  local *= scale;

#pragma unroll
  for (int o = 32; o > 0; o >>= 1) local += __shfl_down(local, o);
  if (lane == 0) wsum[wid] = local;
  __syncthreads();
  if (t == 0) {
    float s = 0.f;
#pragma unroll
    for (int w = 0; w < 8; ++w) s += wsum[w];
    atomicAdd(out, s);
  }
}

}  // namespace

extern "C" void kernel_launch(void* const* d_in, const int* in_sizes, int n_in,
                              void* d_out, int out_size, void* d_ws,
                              size_t ws_size, hipStream_t stream) {
  const float* src = (const float*)d_in[0];
  const float* tgt = (const float*)d_in[1];
  float* out = (float*)d_out;

  // workspace: [sq: 32*1024 f32 = 128 KiB][tot bf16: 32*1024*512*2B = 32 MiB]
  float* sq = (float*)d_ws;
  unsigned int* tot = (unsigned int*)((char*)d_ws + (size_t)kC * kN * 4);

  {
    int blocks = (kN * kC) / 4;   // one wave per (i,c) row, 4 waves/block
    prep_kernel<<<blocks, 256, 0, stream>>>(src, tgt, sq, tot, out);
  }
  {
    int blocks = NP * kC;         // 10 pairs x 32 channels = 320
    mmd_kernel<<<blocks, 512, 0, stream>>>((const unsigned short*)tot, sq, out);
  }
}

// Round 11
// 62.282 us; speedup vs baseline: 1.0592x; 1.0592x over previous
//
#include <hip/hip_runtime.h>

namespace {

constexpr int kC = 32;
constexpr int kD = 512;
constexpr int kB = 512;
constexpr int kN = 1024;               // 2B rows (source ++ target)
constexpr int kCD = kC * kD;           // floats per batch index i
constexpr int BM = 128;                // pair-panel size (128x128 block tile)
constexpr int BKt = 32;                // K chunk (bf16 elements)
constexpr int KT = kD / BKt;           // 16
constexpr int TILES = kN / BM;         // 8 panels per side
constexpr int NP = TILES * (TILES + 1) / 2;  // 36 triangular pairs

typedef float f32x4 __attribute__((ext_vector_type(4)));
typedef short s16x8 __attribute__((ext_vector_type(8)));

// pack two f32 to bf16 (RNE) into one u32: a -> low half, b -> high half
__device__ inline unsigned int pack_bf16(float a, float b) {
  unsigned int ua = __float_as_uint(a);
  unsigned int ub = __float_as_uint(b);
  ua += 0x7fffu + ((ua >> 16) & 1u);   // round-to-nearest-even
  ub += 0x7fffu + ((ub >> 16) & 1u);
  return (ua >> 16) | (ub & 0xffff0000u);
}

// Pass 1: tot[c][i][d] = bf16(total[i,c,d]); sq[c*kN+i] = sum_d total^2 (f32).
// One wave per (i,c) row of 512 floats. Also zeroes d_out (replaces memset).
__global__ void prep_kernel(const float* __restrict__ src,
                            const float* __restrict__ tgt,
                            float* __restrict__ sq,
                            unsigned int* __restrict__ tot,
                            float* __restrict__ out) {
  if (blockIdx.x == 0 && threadIdx.x == 0) *out = 0.f;
  int gw = (blockIdx.x * blockDim.x + threadIdx.x) >> 6;
  int lane = threadIdx.x & 63;
  int i = gw >> 5;
  int c = gw & 31;
  const float* p = (i < kB ? src + (size_t)i * kCD
                           : tgt + (size_t)(i - kB) * kCD) + c * kD;
  f32x4 v0 = *(const f32x4*)(p + lane * 8);
  f32x4 v1 = *(const f32x4*)(p + lane * 8 + 4);

  uint4 w = make_uint4(pack_bf16(v0.x, v0.y), pack_bf16(v0.z, v0.w),
                       pack_bf16(v1.x, v1.y), pack_bf16(v1.z, v1.w));
  *(uint4*)(tot + (size_t)(c * kN + i) * (kD / 2) + lane * 4) = w;

  float s = v0.x * v0.x + v0.y * v0.y + v0.z * v0.z + v0.w * v0.w
          + v1.x * v1.x + v1.y * v1.y + v1.z * v1.z + v1.w * v1.w;
#pragma unroll
  for (int o = 32; o > 0; o >>= 1) s += __shfl_down(s, o);
  if (lane == 0) sq[c * kN + i] = s;
}

// Pass 2: 128x128 pair tile per block, TWO waves of 128x64 each (raises
// FLOP per LDS byte from 32 to 42.7 -- R5's model closed at the 85 B/cyc
// ds_read_b128 wall). 36 pairs x 32 ch = 1152 blocks (4.5/CU; ~4 co-resident
// at 32KB LDS + ~210 VGPR). 2-deep LDS; stage-next issued right after the
// barrier so the single vmcnt(0) per step waits loads issued a full step ago.
// LDS layout per 8KB panel buffer: row r (0..127, 64B), 16B chunk q at byte
// S(r,q) = (r>>1)*128 + (r&1)*64 + (q ^ ((r>>1)&3))*16   [R4..R10-verified].
__launch_bounds__(128, 2)
__global__ void mmd_kernel(const unsigned short* __restrict__ tot,
                           const float* __restrict__ sq,
                           float* __restrict__ out) {
  const int b = blockIdx.x;
  const int c = b & 31;          // b = p*32 + c -> b%8 == c%8 (XCD pin)
  int p = b >> 5;                // 0..35
  int ti = 0;
  while (p >= TILES - ti) { p -= TILES - ti; ++ti; }
  const int tj = ti + p;

  __shared__ __align__(16) unsigned short lA[2][BM * BKt];  // 2 x 8KB
  __shared__ __align__(16) unsigned short lB[2][BM * BKt];
  __shared__ float wsum[2];

  const int t = threadIdx.x;     // 0..127
  const int lane = t & 63;
  const int wid = t >> 6;        // 0..1: wave covers cols wid*64..+63

  const unsigned short* gA = tot + (size_t)(c * kN + ti * BM) * kD;
  const unsigned short* gB = tot + (size_t)(c * kN + tj * BM) * kD;

  // staging: segment s (1KB) covers rows 16s..16s+15; wave w stages segments
  // {4w..4w+3} of A and of B (8 global_load_lds per wave per step).
  // lane l's 16B at linear s*1024+l*16 holds row 16s+srow, chunk scch:
  const int srow = ((lane >> 3) << 1) + ((lane >> 2) & 1);
  const int scch = (lane & 3) ^ ((lane >> 3) & 3);

  auto STAGE = [&](int buf, int ks) {
#pragma unroll
    for (int q = 0; q < 4; ++q) {
      int seg = wid * 4 + q;
      int r = 16 * seg + srow;
      size_t off = (size_t)r * kD + ks * BKt + scch * 8;
      __builtin_amdgcn_global_load_lds(
          (const __attribute__((address_space(1))) unsigned int*)(gA + off),
          (__attribute__((address_space(3))) unsigned int*)&lA[buf][seg * 512],
          16, 0, 0);
      __builtin_amdgcn_global_load_lds(
          (const __attribute__((address_space(1))) unsigned int*)(gB + off),
          (__attribute__((address_space(3))) unsigned int*)&lB[buf][seg * 512],
          16, 0, 0);
    }
  };

  // fragment-read lane offset (bytes): row 16m + (lane&15), k-chunk lane>>4;
  // swizzle term lane-only -> m/n offsets are compile-time immediates.
  const int l15 = lane & 15;
  const int s4 = lane >> 4;
  const int laneoff = ((l15 >> 1) << 7) + ((l15 & 1) << 6) +
                      ((s4 ^ ((l15 >> 1) & 3)) << 4);

  f32x4 acc[8][4] = {};

  STAGE(0, 0);

#pragma unroll
  for (int ks = 0; ks < KT; ++ks) {
    // own stage loads for this buffer were issued a full iteration ago;
    // barrier publishes all waves' completed stages.
    asm volatile("s_waitcnt vmcnt(0)" ::: "memory");
    __builtin_amdgcn_sched_barrier(0);
    __builtin_amdgcn_s_barrier();

    const int buf = ks & 1;
    if (ks + 1 < KT) STAGE(buf ^ 1, ks + 1);   // issue early, wait next iter

    const char* Abase = (const char*)lA[buf] + laneoff;
    const char* Bbase = (const char*)lB[buf] + wid * 4096 + laneoff;
    s16x8 aF[8], bF[4];
#pragma unroll
    for (int m = 0; m < 8; ++m) aF[m] = *(const s16x8*)(Abase + m * 1024);
#pragma unroll
    for (int n = 0; n < 4; ++n) bF[n] = *(const s16x8*)(Bbase + n * 1024);

    __builtin_amdgcn_s_setprio(1);
#pragma unroll
    for (int m = 0; m < 8; ++m)
#pragma unroll
      for (int n = 0; n < 4; ++n)
        acc[m][n] = __builtin_amdgcn_mfma_f32_16x16x32_bf16(
            aF[m], bF[n], acc[m][n], 0, 0, 0);
    __builtin_amdgcn_s_setprio(0);
  }

  // epilogue: L2 = sq_i + sq_j - 2*cross; 5-sigma kernel via repeated
  // squaring. acc[m][n] reg rI -> row ti*128+m*16+s4*4+rI,
  // col tj*128+wid*64+n*16+l15. Diagonal blocks (ti==tj) summed once (whole
  // square = its full contribution); off-diag weighted 2x (symmetry).
  const float sgn = ((ti < TILES / 2) == (tj < TILES / 2)) ? 1.f : -1.f;
  const float scale = sgn * ((ti == tj) ? 1.f : 2.f) / 262144.f;  // / B^2
  const float* sqA = sq + c * kN + ti * BM;
  const float* sqB = sq + c * kN + tj * BM + wid * 64;

  float local = 0.f;
#pragma unroll
  for (int m = 0; m < 8; ++m) {
    float sqa_r[4];
#pragma unroll
    for (int rI = 0; rI < 4; ++rI)
      sqa_r[rI] = sqA[m * 16 + s4 * 4 + rI];
#pragma unroll
    for (int n = 0; n < 4; ++n) {
      float sqb_ = sqB[n * 16 + l15];
#pragma unroll
      for (int rI = 0; rI < 4; ++rI) {
        float L2 = sqa_r[rI] + sqb_ - 2.f * acc[m][n][rI];
        float tt = __expf(L2 * -0.0625f);  // exp(-L2/16)
        float t2 = tt * tt, t4 = t2 * t2, t8 = t4 * t4;
        local += tt + t2 + t4 + t8 + t8 * t8;
      }
    }
  }
  local *= scale;

#pragma unroll
  for (int o = 32; o > 0; o >>= 1) local += __shfl_down(local, o);
  if (lane == 0) wsum[wid] = local;
  __syncthreads();
  if (t == 0) atomicAdd(out, wsum[0] + wsum[1]);
}

}  // namespace

extern "C" void kernel_launch(void* const* d_in, const int* in_sizes, int n_in,
                              void* d_out, int out_size, void* d_ws,
                              size_t ws_size, hipStream_t stream) {
  const float* src = (const float*)d_in[0];
  const float* tgt = (const float*)d_in[1];
  float* out = (float*)d_out;

  // workspace: [sq: 32*1024 f32 = 128 KiB][tot bf16: 32*1024*512*2B = 32 MiB]
  float* sq = (float*)d_ws;
  unsigned int* tot = (unsigned int*)((char*)d_ws + (size_t)kC * kN * 4);

  {
    int blocks = (kN * kC) / 4;   // one wave per (i,c) row, 4 waves/block
    prep_kernel<<<blocks, 256, 0, stream>>>(src, tgt, sq, tot, out);
  }
  {
    int blocks = NP * kC;         // 36 pairs x 32 channels = 1152
    mmd_kernel<<<blocks, 128, 0, stream>>>((const unsigned short*)tot, sq, out);
  }
}

// Round 12
// 62.135 us; speedup vs baseline: 1.0617x; 1.0024x over previous
//
#include <hip/hip_runtime.h>

namespace {

constexpr int kC = 32;
constexpr int kD = 512;
constexpr int kB = 512;
constexpr int kN = 1024;               // 2B rows (source ++ target)
constexpr int kCD = kC * kD;           // floats per batch index i
constexpr int BM = 128;                // pair-panel size (128x128 block tile)
constexpr int KT = kD / 32;            // 16 K-steps of 32
constexpr int TILES = kN / BM;         // 8 panels per side
constexpr int NP = TILES * (TILES + 1) / 2;  // 36 triangular pairs

typedef float f32x4 __attribute__((ext_vector_type(4)));

// f32 -> OCP e4m3fn bits (RNE on normals; denormal rounding below 2^-6)
__device__ inline unsigned int f32_to_e4m3(float x) {
  unsigned int u = __float_as_uint(x);
  unsigned int s = (u >> 24) & 0x80u;
  unsigned int ax = u & 0x7fffffffu;
  if (ax < 0x3c800000u) {              // |x| < 2^-6: e4m3 denormal, step 2^-9
    unsigned int m = (unsigned int)(__uint_as_float(ax) * 512.0f + 0.5f);
    return s | (m > 7u ? 8u : m);      // m==8 -> smallest normal
  }
  if (ax > 0x43e00000u) return s | 0x7eu;   // clamp to 448
  unsigned int r = ax + 0x7ffffu + ((ax >> 20) & 1u);  // RNE at mant bit 20
  unsigned int e = (r >> 23) - 120u;   // rebias 127 -> 7
  return s | (e << 3) | ((r >> 20) & 7u);
}

// Pass 1: one block per (seg = 16 rows, c). Writes:
//   sq[c*kN+i]  (f32, exact from f32 inputs)
//   tot fp8 frag-major: block(c,seg,ks) is 512B at ((c*64+seg)*16+ks)*512,
//   byte (q*128 + slot*8 + b) holds row 16*seg+slot, k = 32*ks + 8*q + b.
// Thread t: slot = t&15 (row), ks = t>>4; converts 32 f32 -> 32 fp8.
__global__ void prep_kernel(const float* __restrict__ src,
                            const float* __restrict__ tgt,
                            float* __restrict__ sq,
                            unsigned char* __restrict__ tot,
                            float* __restrict__ out) {
  if (blockIdx.x == 0 && threadIdx.x == 0) *out = 0.f;
  const int seg = blockIdx.x >> 5;
  const int c = blockIdx.x & 31;
  const int t = threadIdx.x;
  const int slot = t & 15;
  const int ks = t >> 4;

  const int i = seg * 16 + slot;
  const float* p = (i < kB ? src + (size_t)i * kCD
                           : tgt + (size_t)(i - kB) * kCD) + c * kD + ks * 32;

  __shared__ unsigned int stg[2048];   // 8KB fp8 staging (frag-major)
  __shared__ float sqp[256];

  float part = 0.f;
#pragma unroll
  for (int q = 0; q < 4; ++q) {
    f32x4 v0 = *(const f32x4*)(p + q * 8);
    f32x4 v1 = *(const f32x4*)(p + q * 8 + 4);
    part += v0.x * v0.x + v0.y * v0.y + v0.z * v0.z + v0.w * v0.w
          + v1.x * v1.x + v1.y * v1.y + v1.z * v1.z + v1.w * v1.w;
    unsigned int lo = f32_to_e4m3(v0.x) | (f32_to_e4m3(v0.y) << 8) |
                      (f32_to_e4m3(v0.z) << 16) | (f32_to_e4m3(v0.w) << 24);
    unsigned int hi = f32_to_e4m3(v1.x) | (f32_to_e4m3(v1.y) << 8) |
                      (f32_to_e4m3(v1.z) << 16) | (f32_to_e4m3(v1.w) << 24);
    int idx = ks * 128 + q * 32 + slot * 2;
    stg[idx] = lo;
    stg[idx + 1] = hi;
  }
  sqp[t] = part;
  __syncthreads();

  // coalesced 8KB block write
  unsigned char* gout = tot + (size_t)(c * 64 + seg) * 8192;
  ((uint4*)gout)[t * 2]     = ((const uint4*)stg)[t * 2];
  ((uint4*)gout)[t * 2 + 1] = ((const uint4*)stg)[t * 2 + 1];

  if (t < 16) {
    float s = 0.f;
#pragma unroll
    for (int j = 0; j < 16; ++j) s += sqp[t + 16 * j];
    sq[c * kN + seg * 16 + t] = s;
  }
}

// Pass 2: 128x128 pair tile per block (36 pairs x 32 ch = 1152), 4 waves of
// 64x64, fp8 MFMA. Frag-major layout => linear global_load_lds, linear LDS,
// conflict-free ds_read_b64 frags. 3-deep LDS (24KB -> 4 blocks/CU = 16
// waves/CU), counted vmcnt(2) (stage = 2 instrs/wave/step), raw barrier,
// setprio. Diagonal elements of ti==tj blocks forced to L2=0 (exact math).
__launch_bounds__(256, 4)
__global__ void mmd_kernel(const unsigned char* __restrict__ tot,
                           const float* __restrict__ sq,
                           float* __restrict__ out) {
  const int b = blockIdx.x;
  const int c = b & 31;          // b = p*32 + c -> b%8 == c%8 (XCD pin)
  int p = b >> 5;                // 0..35
  int ti = 0;
  while (p >= TILES - ti) { p -= TILES - ti; ++ti; }
  const int tj = ti + p;

  __shared__ __align__(16) unsigned char lA[3][4096];  // 3 x 4KB per panel
  __shared__ __align__(16) unsigned char lB[3][4096];
  __shared__ float wsum[4];

  const int t = threadIdx.x;
  const int lane = t & 63;
  const int wid = t >> 6;        // 0..3
  const int wr = wid >> 1;       // rows 64*wr .. +63 of the 128-tile
  const int wcn = wid & 1;       // cols 64*wcn .. +63

  // stage: wave w loads 1KB (2 segs) of A and of B per step; source blocks
  // are frag-major 512B runs; per-lane source, linear LDS dest.
  const size_t blkA = (size_t)(c * 64 + ti * 8 + 2 * wid + (lane >> 5));
  const size_t blkB = (size_t)(c * 64 + tj * 8 + 2 * wid + (lane >> 5));
  const int loff16 = (lane & 31) * 16;

  auto STAGE = [&](int buf, int ks) {
    const unsigned char* sa = tot + (blkA * 16 + ks) * 512 + loff16;
    const unsigned char* sb = tot + (blkB * 16 + ks) * 512 + loff16;
    __builtin_amdgcn_global_load_lds(
        (const __attribute__((address_space(1))) unsigned int*)sa,
        (__attribute__((address_space(3))) unsigned int*)&lA[buf][wid * 1024],
        16, 0, 0);
    __builtin_amdgcn_global_load_lds(
        (const __attribute__((address_space(1))) unsigned int*)sb,
        (__attribute__((address_space(3))) unsigned int*)&lB[buf][wid * 1024],
        16, 0, 0);
  };

  // frag read (i64 units): seg*64 + (lane>>4)*16 + (lane&15)
  const int fo = ((lane >> 4) << 4) + (lane & 15);

  f32x4 acc[4][4] = {};

  STAGE(0, 0);
  STAGE(1, 1);

#pragma unroll
  for (int ks = 0; ks < KT; ++ks) {
    // wait this step's buffer only; next step's 2 loads stay in flight (T4)
    if (ks + 1 < KT) asm volatile("s_waitcnt vmcnt(2)" ::: "memory");
    else             asm volatile("s_waitcnt vmcnt(0)" ::: "memory");
    __builtin_amdgcn_sched_barrier(0);
    __builtin_amdgcn_s_barrier();

    const int buf = ks % 3;
    const long* A64 = (const long*)lA[buf];
    const long* B64 = (const long*)lB[buf];
    long aF[4], bF[4];
#pragma unroll
    for (int m = 0; m < 4; ++m) aF[m] = A64[(4 * wr + m) * 64 + fo];
#pragma unroll
    for (int n = 0; n < 4; ++n) bF[n] = B64[(4 * wcn + n) * 64 + fo];

    // overwrites buf (ks-1)%3: all waves' reads of it completed before this
    // iteration's barrier (lgkmcnt drained by their consuming MFMAs).
    if (ks + 2 < KT) STAGE((ks + 2) % 3, ks + 2);

    __builtin_amdgcn_s_setprio(1);
#pragma unroll
    for (int m = 0; m < 4; ++m)
#pragma unroll
      for (int n = 0; n < 4; ++n)
        acc[m][n] = __builtin_amdgcn_mfma_f32_16x16x32_fp8_fp8(
            aF[m], bF[n], acc[m][n], 0, 0, 0);
    __builtin_amdgcn_s_setprio(0);
  }

  // epilogue: L2 = sq_i + sq_j - 2*cross; 5-sigma kernel via repeated
  // squaring. acc[m][n] reg rI -> local row wr*64+m*16+(lane>>4)*4+rI,
  // local col wcn*64+n*16+(lane&15). Diag blocks: full square, weight 1;
  // off-diag: weight 2. gr==gc on diag blocks: L2 = 0 identically (exact).
  const float sgn = ((ti < TILES / 2) == (tj < TILES / 2)) ? 1.f : -1.f;
  const bool diag = (ti == tj);
  const float scale = sgn * (diag ? 1.f : 2.f) / 262144.f;  // / B^2
  const float* sqA = sq + c * kN + ti * BM + wr * 64;
  const float* sqB = sq + c * kN + tj * BM + wcn * 64;
  const int s4 = lane >> 4, l15 = lane & 15;

  float local = 0.f;
#pragma unroll
  for (int m = 0; m < 4; ++m) {
    float sqa_r[4];
#pragma unroll
    for (int rI = 0; rI < 4; ++rI)
      sqa_r[rI] = sqA[m * 16 + s4 * 4 + rI];
#pragma unroll
    for (int n = 0; n < 4; ++n) {
      float sqb_ = sqB[n * 16 + l15];
#pragma unroll
      for (int rI = 0; rI < 4; ++rI) {
        float L2 = sqa_r[rI] + sqb_ - 2.f * acc[m][n][rI];
        if (diag && (wr * 64 + m * 16 + s4 * 4 + rI) ==
                    (wcn * 64 + n * 16 + l15))
          L2 = 0.f;                    // ||x_i - x_i||^2 == 0 identically
        float tt = __expf(L2 * -0.0625f);  // exp(-L2/16)
        float t2 = tt * tt, t4 = t2 * t2, t8 = t4 * t4;
        local += tt + t2 + t4 + t8 + t8 * t8;
      }
    }
  }
  local *= scale;

#pragma unroll
  for (int o = 32; o > 0; o >>= 1) local += __shfl_down(local, o);
  if (lane == 0) wsum[wid] = local;
  __syncthreads();
  if (t == 0)
    atomicAdd(out, wsum[0] + wsum[1] + wsum[2] + wsum[3]);
}

}  // namespace

extern "C" void kernel_launch(void* const* d_in, const int* in_sizes, int n_in,
                              void* d_out, int out_size, void* d_ws,
                              size_t ws_size, hipStream_t stream) {
  const float* src = (const float*)d_in[0];
  const float* tgt = (const float*)d_in[1];
  float* out = (float*)d_out;

  // workspace: [sq: 32*1024 f32 = 128 KiB][tot fp8 frag-major: 16.78 MiB]
  float* sq = (float*)d_ws;
  unsigned char* tot = (unsigned char*)d_ws + (size_t)kC * kN * 4;

  {
    int blocks = 64 * kC;         // one block per (16-row seg, channel)
    prep_kernel<<<blocks, 256, 0, stream>>>(src, tgt, sq, tot, out);
  }
  {
    int blocks = NP * kC;         // 36 pairs x 32 channels = 1152
    mmd_kernel<<<blocks, 256, 0, stream>>>(tot, sq, out);
  }
}

// Round 13
// 61.207 us; speedup vs baseline: 1.0778x; 1.0152x over previous
//
#include <hip/hip_runtime.h>

namespace {

constexpr int kC = 32;
constexpr int kD = 512;
constexpr int kB = 512;
constexpr int kN = 1024;               // 2B rows (source ++ target)
constexpr int kCD = kC * kD;           // floats per batch index i
constexpr int BM = 128;                // pair-panel size (128x128 block tile)
constexpr int KT2 = kD / 64;           // 8 K-steps of 64
constexpr int TILES = kN / BM;         // 8 panels per side
constexpr int NP = TILES * (TILES + 1) / 2;  // 36 triangular pairs

typedef float f32x4 __attribute__((ext_vector_type(4)));

// f32 -> OCP e4m3fn bits (RNE on normals; denormal rounding below 2^-6)
__device__ inline unsigned int f32_to_e4m3(float x) {
  unsigned int u = __float_as_uint(x);
  unsigned int s = (u >> 24) & 0x80u;
  unsigned int ax = u & 0x7fffffffu;
  if (ax < 0x3c800000u) {              // |x| < 2^-6: e4m3 denormal, step 2^-9
    unsigned int m = (unsigned int)(__uint_as_float(ax) * 512.0f + 0.5f);
    return s | (m > 7u ? 8u : m);      // m==8 -> smallest normal
  }
  if (ax > 0x43e00000u) return s | 0x7eu;   // clamp to 448
  unsigned int r = ax + 0x7ffffu + ((ax >> 20) & 1u);  // RNE at mant bit 20
  unsigned int e = (r >> 23) - 120u;   // rebias 127 -> 7
  return s | (e << 3) | ((r >> 20) & 7u);
}

// Pass 1: one block per (seg = 16 rows, c). Writes:
//   sq[c*kN+i]  (f32, exact from f32 inputs)
//   tot fp8 frag-major: block(c,seg,ks) is 512B at ((c*64+seg)*16+ks)*512,
//   byte (q*128 + slot*8 + b) holds row 16*seg+slot, k = 32*ks + 8*q + b.
// Thread t: slot = t>>4 (row), ks = t&15  -> 16 consecutive lanes tile one
// row's 2KB contiguously (R12 had slot=t&15: lanes 64KB apart, uncoalesced).
__global__ void prep_kernel(const float* __restrict__ src,
                            const float* __restrict__ tgt,
                            float* __restrict__ sq,
                            unsigned char* __restrict__ tot,
                            float* __restrict__ out) {
  if (blockIdx.x == 0 && threadIdx.x == 0) *out = 0.f;
  const int seg = blockIdx.x >> 5;
  const int c = blockIdx.x & 31;
  const int t = threadIdx.x;
  const int slot = t >> 4;
  const int ks = t & 15;

  const int i = seg * 16 + slot;
  const float* p = (i < kB ? src + (size_t)i * kCD
                           : tgt + (size_t)(i - kB) * kCD) + c * kD + ks * 32;

  __shared__ unsigned int stg[2048];   // 8KB fp8 staging (frag-major)
  __shared__ float sqp[256];

  float part = 0.f;
#pragma unroll
  for (int q = 0; q < 4; ++q) {
    f32x4 v0 = *(const f32x4*)(p + q * 8);
    f32x4 v1 = *(const f32x4*)(p + q * 8 + 4);
    part += v0.x * v0.x + v0.y * v0.y + v0.z * v0.z + v0.w * v0.w
          + v1.x * v1.x + v1.y * v1.y + v1.z * v1.z + v1.w * v1.w;
    unsigned int lo = f32_to_e4m3(v0.x) | (f32_to_e4m3(v0.y) << 8) |
                      (f32_to_e4m3(v0.z) << 16) | (f32_to_e4m3(v0.w) << 24);
    unsigned int hi = f32_to_e4m3(v1.x) | (f32_to_e4m3(v1.y) << 8) |
                      (f32_to_e4m3(v1.z) << 16) | (f32_to_e4m3(v1.w) << 24);
    int idx = ks * 128 + q * 32 + slot * 2;
    stg[idx] = lo;
    stg[idx + 1] = hi;
  }
  sqp[t] = part;
  __syncthreads();

  // coalesced 8KB block write
  unsigned char* gout = tot + (size_t)(c * 64 + seg) * 8192;
  ((uint4*)gout)[t * 2]     = ((const uint4*)stg)[t * 2];
  ((uint4*)gout)[t * 2 + 1] = ((const uint4*)stg)[t * 2 + 1];

  if (t < 16) {
    float s = 0.f;
#pragma unroll
    for (int j = 0; j < 16; ++j) s += sqp[t * 16 + j];
    sq[c * kN + seg * 16 + t] = s;
  }
}

// Pass 2: 128x128 pair tile per block (36 pairs x 32 ch = 1152), 4 waves of
// 64x64, fp8 MFMA, BK=64 (8 barrier-steps instead of 16). Frag-major layout
// makes each seg's two 512B k-chunks CONTIGUOUS 1KB -> staging is 4 linear
// global_load_lds per wave per step. 2-deep LDS (32KB -> 4 blocks/CU);
// stage-next issued right after the barrier so vmcnt(0) waits loads issued a
// full phase earlier. Diag elements of ti==tj blocks forced to L2=0 (exact).
__launch_bounds__(256, 4)
__global__ void mmd_kernel(const unsigned char* __restrict__ tot,
                           const float* __restrict__ sq,
                           float* __restrict__ out) {
  const int b = blockIdx.x;
  const int c = b & 31;          // b = p*32 + c -> b%8 == c%8 (XCD pin)
  int p = b >> 5;                // 0..35
  int ti = 0;
  while (p >= TILES - ti) { p -= TILES - ti; ++ti; }
  const int tj = ti + p;

  __shared__ __align__(16) unsigned char lA[2][8192];  // 8 segs x 2 chunks
  __shared__ __align__(16) unsigned char lB[2][8192];
  __shared__ float wsum[4];

  const int t = threadIdx.x;
  const int lane = t & 63;
  const int wid = t >> 6;        // 0..3
  const int wr = wid >> 1;       // rows 64*wr .. +63 of the 128-tile
  const int wcn = wid & 1;       // cols 64*wcn .. +63

  const int blkA0 = c * 64 + ti * 8;   // 512B-block index base of A panel
  const int blkB0 = c * 64 + tj * 8;

  auto STAGE = [&](int buf, int kt) {
#pragma unroll
    for (int q = 0; q < 2; ++q) {
      int seg = wid * 2 + q;
      const unsigned char* sa =
          tot + ((size_t)(blkA0 + seg) * 16 + 2 * kt) * 512 + lane * 16;
      const unsigned char* sb =
          tot + ((size_t)(blkB0 + seg) * 16 + 2 * kt) * 512 + lane * 16;
      __builtin_amdgcn_global_load_lds(
          (const __attribute__((address_space(1))) unsigned int*)sa,
          (__attribute__((address_space(3))) unsigned int*)&lA[buf][seg * 1024],
          16, 0, 0);
      __builtin_amdgcn_global_load_lds(
          (const __attribute__((address_space(1))) unsigned int*)sb,
          (__attribute__((address_space(3))) unsigned int*)&lB[buf][seg * 1024],
          16, 0, 0);
    }
  };

  // frag read (i64 units within a 1KB seg): chunk pi*64 + (lane>>4)*16 + (lane&15)
  const int fo = ((lane >> 4) << 4) + (lane & 15);

  f32x4 acc[4][4] = {};

  STAGE(0, 0);

#pragma unroll
  for (int kt = 0; kt < KT2; ++kt) {
    // own stage loads for this buffer were issued a full phase ago; barrier
    // publishes all waves' completed stages.
    asm volatile("s_waitcnt vmcnt(0)" ::: "memory");
    __builtin_amdgcn_sched_barrier(0);
    __builtin_amdgcn_s_barrier();

    const int buf = kt & 1;
    if (kt + 1 < KT2) STAGE(buf ^ 1, kt + 1);   // issue early, wait next iter

    const long* A64 = (const long*)lA[buf];
    const long* B64 = (const long*)lB[buf];
    long aF[2][4], bF[2][4];
#pragma unroll
    for (int pi = 0; pi < 2; ++pi) {
#pragma unroll
      for (int m = 0; m < 4; ++m)
        aF[pi][m] = A64[(4 * wr + m) * 128 + pi * 64 + fo];
#pragma unroll
      for (int n = 0; n < 4; ++n)
        bF[pi][n] = B64[(4 * wcn + n) * 128 + pi * 64 + fo];
    }

    __builtin_amdgcn_s_setprio(1);
#pragma unroll
    for (int pi = 0; pi < 2; ++pi)
#pragma unroll
      for (int m = 0; m < 4; ++m)
#pragma unroll
        for (int n = 0; n < 4; ++n)
          acc[m][n] = __builtin_amdgcn_mfma_f32_16x16x32_fp8_fp8(
              aF[pi][m], bF[pi][n], acc[m][n], 0, 0, 0);
    __builtin_amdgcn_s_setprio(0);
  }

  // epilogue: L2 = sq_i + sq_j - 2*cross; 5-sigma kernel via repeated
  // squaring. acc[m][n] reg rI -> local row wr*64+m*16+(lane>>4)*4+rI,
  // local col wcn*64+n*16+(lane&15). Diag blocks: full square, weight 1;
  // off-diag: weight 2. gr==gc on diag blocks: L2 = 0 identically (exact).
  const float sgn = ((ti < TILES / 2) == (tj < TILES / 2)) ? 1.f : -1.f;
  const bool diag = (ti == tj);
  const float scale = sgn * (diag ? 1.f : 2.f) / 262144.f;  // / B^2
  const float* sqA = sq + c * kN + ti * BM + wr * 64;
  const float* sqB = sq + c * kN + tj * BM + wcn * 64;
  const int s4 = lane >> 4, l15 = lane & 15;

  float local = 0.f;
#pragma unroll
  for (int m = 0; m < 4; ++m) {
    float sqa_r[4];
#pragma unroll
    for (int rI = 0; rI < 4; ++rI)
      sqa_r[rI] = sqA[m * 16 + s4 * 4 + rI];
#pragma unroll
    for (int n = 0; n < 4; ++n) {
      float sqb_ = sqB[n * 16 + l15];
#pragma unroll
      for (int rI = 0; rI < 4; ++rI) {
        float L2 = sqa_r[rI] + sqb_ - 2.f * acc[m][n][rI];
        if (diag && (wr * 64 + m * 16 + s4 * 4 + rI) ==
                    (wcn * 64 + n * 16 + l15))
          L2 = 0.f;                    // ||x_i - x_i||^2 == 0 identically
        float tt = __expf(L2 * -0.0625f);  // exp(-L2/16)
        float t2 = tt * tt, t4 = t2 * t2, t8 = t4 * t4;
        local += tt + t2 + t4 + t8 + t8 * t8;
      }
    }
  }
  local *= scale;

#pragma unroll
  for (int o = 32; o > 0; o >>= 1) local += __shfl_down(local, o);
  if (lane == 0) wsum[wid] = local;
  __syncthreads();
  if (t == 0)
    atomicAdd(out, wsum[0] + wsum[1] + wsum[2] + wsum[3]);
}

}  // namespace

extern "C" void kernel_launch(void* const* d_in, const int* in_sizes, int n_in,
                              void* d_out, int out_size, void* d_ws,
                              size_t ws_size, hipStream_t stream) {
  const float* src = (const float*)d_in[0];
  const float* tgt = (const float*)d_in[1];
  float* out = (float*)d_out;

  // workspace: [sq: 32*1024 f32 = 128 KiB][tot fp8 frag-major: 16.78 MiB]
  float* sq = (float*)d_ws;
  unsigned char* tot = (unsigned char*)d_ws + (size_t)kC * kN * 4;

  {
    int blocks = 64 * kC;         // one block per (16-row seg, channel)
    prep_kernel<<<blocks, 256, 0, stream>>>(src, tgt, sq, tot, out);
  }
  {
    int blocks = NP * kC;         // 36 pairs x 32 channels = 1152
    mmd_kernel<<<blocks, 256, 0, stream>>>(tot, sq, out);
  }
}